// Round 6
// baseline (668.468 us; speedup 1.0000x reference)
//
#include <hip/hip_runtime.h>

// ---------------------------------------------------------------------------
// SublayerConnection: MHA + residual/LN + FF + residual/LN
// B=4 S=2048 D=1024 H=16 Dk=64 Dff=4096.
// Round 10: (1) attn launch_bounds (256,4)->(256,3): round-5's 64-VGPR
// squeeze caused per-iter scratch spills (WRITE 48.6MB vs 16.4MB ctx).
// (256,3) gave 76 regs / zero scratch in round 4; with LDS now 32KB the
// HW occupancy is LDS-capped at 5 blocks/CU anyway. (2) ln_dual/ln_final
// -> wave-per-row (4 rows/block): no LDS, no barriers, 4x work per block.
// GEMMs (round-5 DBUF, proven) untouched.
// ---------------------------------------------------------------------------

#define DM   1024
#define DFF  4096
#define SEQ  2048

typedef unsigned short u16;
typedef short          sx8  __attribute__((ext_vector_type(8)));
typedef unsigned short ushx8 __attribute__((ext_vector_type(8)));
typedef unsigned short ushx4 __attribute__((ext_vector_type(4)));
typedef float          fx4  __attribute__((ext_vector_type(4)));
typedef unsigned int   ux2  __attribute__((ext_vector_type(2)));

__device__ __forceinline__ void async16(const void* g, void* l) {
  __builtin_amdgcn_global_load_lds((__attribute__((address_space(1))) void*)g,
                                   (__attribute__((address_space(3))) void*)l,
                                   16, 0, 0);
}
__device__ __forceinline__ float b2f(u16 u) {
  union { unsigned int i; float f; } v; v.i = ((unsigned int)u) << 16; return v.f;
}
__device__ __forceinline__ u16 f2b(float f) {
  union { float f; unsigned int i; } v; v.f = f;
  unsigned int r = v.i + 0x7fffu + ((v.i >> 16) & 1u);
  return (u16)(r >> 16);
}
__device__ __forceinline__ float fexp2(float x) {
#if __has_builtin(__builtin_amdgcn_exp2f)
  return __builtin_amdgcn_exp2f(x);
#else
  return exp2f(x);
#endif
}
__device__ __forceinline__ ushx8 ld8(const void* p, long idx, bool f32) {
  if (f32) {
    const float* s = (const float*)p + idx;
    fx4 a = *(const fx4*)s, b = *(const fx4*)(s + 4);
    ushx8 r;
    r[0] = f2b(a[0]); r[1] = f2b(a[1]); r[2] = f2b(a[2]); r[3] = f2b(a[3]);
    r[4] = f2b(b[0]); r[5] = f2b(b[1]); r[6] = f2b(b[2]); r[7] = f2b(b[3]);
    return r;
  }
  return *(const ushx8*)((const u16*)p + idx);
}
__device__ __forceinline__ void ld4f(const void* p, long idx, bool f32, float* o) {
  if (f32) {
    fx4 a = *(const fx4*)((const float*)p + idx);
    o[0] = a[0]; o[1] = a[1]; o[2] = a[2]; o[3] = a[3];
  } else {
    ushx4 a = *(const ushx4*)((const u16*)p + idx);
    o[0] = b2f(a[0]); o[1] = b2f(a[1]); o[2] = b2f(a[2]); o[3] = b2f(a[3]);
  }
}

// ---------------------------------------------------------------------------
__global__ void detect_kernel(const void* q, int* flags) {
  int lane = threadIdx.x;
  u16 v = ((const u16*)q)[lane << 1];
  int e = (v >> 7) & 0xff;
  int pl = (e >= 0x60 && e <= 0x8c) ? 1 : 0;
  unsigned long long m = __ballot(pl);
  if (lane == 0) { flags[0] = (__popcll(m) >= 40) ? 0 : 1; flags[1] = 0; flags[2] = 1; }
}

// Scan mask for any zero; flags[2] stays 1 iff every element nonzero.
__global__ __launch_bounds__(256)
void mask_scan(const int* __restrict__ m, int* flags) {
  long i = (((long)blockIdx.x << 8) + threadIdx.x) << 3;
  const int4 a = *(const int4*)(m + i);
  const int4 b = *(const int4*)(m + i + 4);
  bool ok = a.x && a.y && a.z && a.w && b.x && b.y && b.z && b.w;
  if (!__all(ok)) { if ((threadIdx.x & 63) == 0) flags[2] = 0; }
}

// Pack Wq/Wk/Wv -> Wqkv [3*1024,1024] bf16 and Wo -> bf16.
__global__ __launch_bounds__(256)
void pack_w(const void* Wq, const void* Wk, const void* Wv, const void* Wo,
            u16* Wqkv, u16* Wo_bf, const int* f_p) {
  const bool f = (*f_p != 0);
  long i = (((long)blockIdx.x << 8) + threadIdx.x) << 3;
  const long QKVN = (long)3 * DM * DM;
  if (i < QKVN) {
    int row = (int)(i >> 10);
    const void* src = (row < DM) ? Wq : (row < 2 * DM ? Wk : Wv);
    long s = ((long)(row & (DM - 1)) << 10) + (i & 1023);
    *(ushx8*)(Wqkv + i) = ld8(src, s, f);
  } else {
    long j = i - QKVN;
    *(ushx8*)(Wo_bf + j) = ld8(Wo, j, f);
  }
}

// Convert q/k/v chunk to bf16; grid.y selects source, dst stride n.
__global__ __launch_bounds__(256)
void conv_bf3(const void* q, const void* k, const void* v, long off,
              u16* dst, long n, const int* f_p) {
  const bool f = (*f_p != 0);
  const void* src = (blockIdx.y == 0) ? q : (blockIdx.y == 1 ? k : v);
  long i = (((long)blockIdx.x << 8) + threadIdx.x) << 3;
  if (i < n) *(ushx8*)(dst + (long)blockIdx.y * n + i) = ld8(src, off + i, f);
}

// ---------------------------------------------------------------------------
// Pure-bf16 NT GEMM with global_load_lds(16B) staging. C=A@B^T (+bias)(+relu).
// grid.y = z selects (A,B,C) via element strides az/bz/cz. C row stride ldc.
// DBUF: 2 LDS buffers (64KB -> 2 blocks/CU), prefetch-next then vmcnt(8)
// BEFORE the pre-compute raw barrier (cross-wave sound); prefetch spans
// the compute. All grids %8==0 -> bijective XCD swizzle.
// ---------------------------------------------------------------------------
template<bool RELU, bool BIAS, bool DBUF>
__global__ __launch_bounds__(256)
void gemm_bb(const u16* __restrict__ A, long az, const u16* __restrict__ B, long bz,
             const void* __restrict__ bias, u16* __restrict__ C, long cz,
             int M, int N, int K, int ldc, const int* biasf_p) {
  __shared__ __align__(16) u16 sA[(DBUF ? 2 : 1) * 128 * 64];
  __shared__ __align__(16) u16 sB[(DBUF ? 2 : 1) * 128 * 64];
  const int z = blockIdx.y;
  A += (long)z * az; B += (long)z * bz; C += (long)z * cz;
  const bool biasf = BIAS && (*biasf_p != 0);
  const int t = threadIdx.x;
  const int lane = t & 63, w = t >> 6;
  const int lm = lane & 15, lg = lane >> 4;
  const int ntil = N >> 7;
  // XCD-aware bijective swizzle (gridDim.x % 8 == 0 for all dispatches)
  const int bx = (blockIdx.x & 7) * ((int)gridDim.x >> 3) + (blockIdx.x >> 3);
  const int m0 = (bx / ntil) << 7;
  const int n0 = (bx % ntil) << 7;
  const int wm = (w & 1) << 6, wn = (w >> 1) << 6;

  fx4 acc[4][4];
#pragma unroll
  for (int i = 0; i < 4; ++i)
#pragma unroll
    for (int j = 0; j < 4; ++j) acc[i][j] = (fx4){0.f, 0.f, 0.f, 0.f};

  auto stage = [&](int so, int kt) {
#pragma unroll
    for (int it = 0; it < 4; ++it) {
      int ci = (it << 8) + t;
      int r = ci >> 3, cs = (ci & 7) ^ (r & 7);
      async16(&A[(size_t)(m0 + r) * K + kt + (cs << 3)], &sA[so + (ci << 3)]);
    }
#pragma unroll
    for (int it = 0; it < 4; ++it) {
      int ci = (it << 8) + t;
      int r = ci >> 3, cs = (ci & 7) ^ (r & 7);
      async16(&B[(size_t)(n0 + r) * K + kt + (cs << 3)], &sB[so + (ci << 3)]);
    }
  };

  auto compute = [&](int so) {
#pragma unroll
    for (int s = 0; s < 2; ++s) {
      const int g = (s << 2) + lg;
      sx8 afr[4], bfr[4];
#pragma unroll
      for (int i = 0; i < 4; ++i) {
        int ra = wm + (i << 4) + lm;
        afr[i] = *(const sx8*)&sA[so + ra * 64 + ((g ^ (ra & 7)) << 3)];
        int rb = wn + (i << 4) + lm;
        bfr[i] = *(const sx8*)&sB[so + rb * 64 + ((g ^ (rb & 7)) << 3)];
      }
      __builtin_amdgcn_s_setprio(1);
#pragma unroll
      for (int i = 0; i < 4; ++i)
#pragma unroll
        for (int j = 0; j < 4; ++j)
          acc[i][j] = __builtin_amdgcn_mfma_f32_16x16x32_bf16(afr[i], bfr[j], acc[i][j], 0, 0, 0);
      __builtin_amdgcn_s_setprio(0);
    }
  };

  if (DBUF) {
    const int NT = K >> 6;
    stage(0, 0);
    for (int n = 0; n < NT; ++n) {
      if (n + 1 < NT) {
        stage(((n + 1) & 1) << 13, (n + 1) << 6);   // prefetch next tile
        asm volatile("s_waitcnt vmcnt(8)" ::: "memory");  // own tile-n landed
      } else {
        asm volatile("s_waitcnt vmcnt(0)" ::: "memory");
      }
      __builtin_amdgcn_s_barrier();                 // all waves' tile-n landed
      __builtin_amdgcn_sched_barrier(0);
      compute((n & 1) << 13);
      if (n + 1 < NT) __builtin_amdgcn_s_barrier(); // buf free before restage
    }
  } else {
    for (int kt = 0; kt < K; kt += 64) {
      __syncthreads();
      stage(0, kt);
      __syncthreads();
      compute(0);
    }
  }

#pragma unroll
  for (int j = 0; j < 4; ++j) {
    const int col = n0 + wn + (j << 4) + lm;
    float bv = 0.f;
    if (BIAS) bv = biasf ? ((const float*)bias)[col] : b2f(((const u16*)bias)[col]);
#pragma unroll
    for (int i = 0; i < 4; ++i) {
      const int row0 = m0 + wm + (i << 4) + (lg << 2);
#pragma unroll
      for (int r = 0; r < 4; ++r) {
        float v = acc[i][j][r] + bv;
        if (RELU) v = fmaxf(v, 0.f);
        C[(size_t)(row0 + r) * ldc + col] = f2b(v);
      }
    }
  }
}

// ---------------------------------------------------------------------------
// Flag-dtype NT GEMM (legacy path, proven in round 3).
// ---------------------------------------------------------------------------
template<bool RELU, bool BIAS>
__global__ __launch_bounds__(256)
void gemm_nt(const void* __restrict__ A, long aoff, const void* __restrict__ Bm,
             const void* __restrict__ bias, u16* __restrict__ C,
             int M, int N, int K,
             const int* af_p, const int* bf_p, const int* biasf_p) {
  __shared__ __align__(16) u16 sA[128 * 64];
  __shared__ __align__(16) u16 sB[128 * 64];
  const bool af = (*af_p != 0), bfl = (*bf_p != 0), biasf = (*biasf_p != 0);
  const int t = threadIdx.x;
  const int lane = t & 63, w = t >> 6;
  const int lm = lane & 15, lg = lane >> 4;
  const int ntil = N >> 7;
  const int m0 = (blockIdx.x / ntil) << 7;
  const int n0 = (blockIdx.x % ntil) << 7;
  const int wm = (w & 1) << 6, wn = (w >> 1) << 6;

  fx4 acc[4][4];
#pragma unroll
  for (int i = 0; i < 4; ++i)
#pragma unroll
    for (int j = 0; j < 4; ++j) acc[i][j] = (fx4){0.f, 0.f, 0.f, 0.f};

  for (int kt = 0; kt < K; kt += 64) {
    __syncthreads();
#pragma unroll
    for (int it = 0; it < 4; ++it) {
      int ci = (it << 8) + t;
      int r = ci >> 3, cs = (ci & 7) ^ (r & 7);
      ushx8 va = ld8(A, aoff + (long)(m0 + r) * K + kt + (cs << 3), af);
      *(ushx8*)&sA[ci << 3] = va;
      ushx8 vb = ld8(Bm, (long)(n0 + r) * K + kt + (cs << 3), bfl);
      *(ushx8*)&sB[ci << 3] = vb;
    }
    __syncthreads();
#pragma unroll
    for (int s = 0; s < 2; ++s) {
      const int g = (s << 2) + lg;
      sx8 afr[4], bfr[4];
#pragma unroll
      for (int i = 0; i < 4; ++i) {
        int ra = wm + (i << 4) + lm;
        afr[i] = *(const sx8*)&sA[ra * 64 + ((g ^ (ra & 7)) << 3)];
        int rb = wn + (i << 4) + lm;
        bfr[i] = *(const sx8*)&sB[rb * 64 + ((g ^ (rb & 7)) << 3)];
      }
#pragma unroll
      for (int i = 0; i < 4; ++i)
#pragma unroll
        for (int j = 0; j < 4; ++j)
          acc[i][j] = __builtin_amdgcn_mfma_f32_16x16x32_bf16(afr[i], bfr[j], acc[i][j], 0, 0, 0);
    }
  }

#pragma unroll
  for (int j = 0; j < 4; ++j) {
    const int col = n0 + wn + (j << 4) + lm;
    float bv = 0.f;
    if (BIAS) bv = biasf ? ((const float*)bias)[col] : b2f(((const u16*)bias)[col]);
#pragma unroll
    for (int i = 0; i < 4; ++i) {
      const int row0 = m0 + wm + (i << 4) + (lg << 2);
#pragma unroll
      for (int r = 0; r < 4; ++r) {
        float v = acc[i][j][r] + bv;
        if (RELU) v = fmaxf(v, 0.f);
        C[(size_t)(row0 + r) * N + col] = f2b(v);
      }
    }
  }
}

// ---------------------------------------------------------------------------
__global__ __launch_bounds__(256)
void transpose_any(const void* __restrict__ in, u16* __restrict__ out,
                   int R, int C, const int* f_p) {
  __shared__ u16 tile[64][68];
  const bool f = (*f_p != 0);
  const int r0 = blockIdx.y << 6, c0 = blockIdx.x << 6;
  const int t = threadIdx.x;
#pragma unroll
  for (int it = 0; it < 4; ++it) {
    int j = (it << 8) + t;
    int rr = j >> 4, cc4 = (j & 15) << 2;
    float v[4];
    ld4f(in, (long)(r0 + rr) * C + c0 + cc4, f, v);
#pragma unroll
    for (int q = 0; q < 4; ++q) tile[rr][cc4 + q] = f2b(v[q]);
  }
  __syncthreads();
#pragma unroll
  for (int it = 0; it < 4; ++it) {
    int j = (it << 8) + t;
    int cc = j >> 4, rr4 = (j & 15) << 2;
    ushx4 v;
    v[0] = tile[rr4 + 0][cc]; v[1] = tile[rr4 + 1][cc];
    v[2] = tile[rr4 + 2][cc]; v[3] = tile[rr4 + 3][cc];
    *(ushx4*)&out[(size_t)(c0 + cc) * R + r0 + rr4] = v;
  }
}

// ---------------------------------------------------------------------------
// Flash attention, swapped-QK^T. grid.x = 512 (XCD-swizzled); grid.y = batch.
// Per wave 16 q rows; lane (lm,lg) owns softmax row q=lm for k=nt*16+lg*4+r.
// K via global_load_lds. V prefetched in 4 NAMED uint4 regs. sVt in GEMM-
// style [128][64] XOR-granule layout (0-conflict PV reads). P LDS aliases
// sK. LDS = 32KB. launch_bounds (256,3): round-5's (256,4) squeezed VGPR
// to 64 -> per-iter scratch spill (WRITE_SIZE 3x). HW occupancy is LDS-
// capped at 5 blocks/CU with ~90 VGPRs anyway.
// ---------------------------------------------------------------------------
__global__ __launch_bounds__(256, 3)
void attn_kernel(const u16* __restrict__ qp, const u16* __restrict__ kp,
                 const u16* __restrict__ vp, int lds_,
                 const int* __restrict__ mask, u16* __restrict__ ctx,
                 const int* __restrict__ mflag) {
  __shared__ __align__(16) u16 smem[16384];   // 32KB: sK(16K)|sVt(16K); sP aliases sK
  u16* const sK  = smem;
  u16* const sVt = smem + 8192;
  unsigned* const sPal = (unsigned*)smem;

  const bool nomask = (*mflag != 0);
  const long boff = (long)blockIdx.y * SEQ * (long)lds_;
  qp += boff; kp += boff; vp += boff;
  mask += (size_t)blockIdx.y * ((size_t)SEQ * SEQ);
  ctx += (size_t)blockIdx.y * ((size_t)SEQ * DM);

  const int id = (blockIdx.x & 7) * ((int)gridDim.x >> 3) + (blockIdx.x >> 3);
  const int q0 = (id & 31) << 6;
  const int h  = id >> 5;
  const int t = threadIdx.x, lane = t & 63, w = t >> 6;
  const int hoff = h << 6;
  const int lm = lane & 15, lg = lane >> 4;
  const int myq = q0 + (w << 4) + lm;        // this lane's softmax row
  const int aslot = 20 * lg;                  // shfl src: lane lg*16 + (lg*4+r)

  // staging geometry
  const int kq = (t & 31) << 2, dg = (t >> 5) << 3;
  const int kg7 = (kq >> 3) & 7;              // thread's k-quad granule
  const int k7o = kq & 7;                     // offset within granule (0 or 4)
  const int vbrow = ((kq >> 6) << 6) + dg;    // sVt base row for writes
  unsigned* pw = sPal + (w << 10);
  const int wswz = (lm & 7) << 2;
  const int pwb = lm << 6;

  // Q fragments: row myq, octets lg and 4+lg
  sx8 aq[2];
#pragma unroll
  for (int s = 0; s < 2; ++s)
    aq[s] = *(const sx8*)&qp[(size_t)myq * lds_ + hoff + (((s << 2) + lg) << 3)];

  fx4 o[4];
#pragma unroll
  for (int i = 0; i < 4; ++i) o[i] = (fx4){0.f, 0.f, 0.f, 0.f};
  float m_prev = -1e30f, lsum = 0.f;
  const float SCL = 0.18033688f;    // 0.125 * log2(e)
  const float RTHR = 44.36142f;     // 8 / SCL (defer-max bound, raw domain)

  // V prefetch (tile 0) in NAMED registers
  const u16* vbase = vp + (size_t)kq * lds_ + hoff + dg;
  uint4 va = *(const uint4*)(vbase);
  uint4 vb_ = *(const uint4*)(vbase + (size_t)lds_);
  uint4 vc = *(const uint4*)(vbase + 2 * (size_t)lds_);
  uint4 vd = *(const uint4*)(vbase + 3 * (size_t)lds_);

  for (int kt = 0; kt < 16; ++kt) {
    const int k0 = kt << 7;
    __syncthreads();                 // prev compute done; LDS reusable
    // K -> sK via global_load_lds (swizzled source, linear LDS)
#pragma unroll
    for (int it = 0; it < 4; ++it) {
      int ci = (it << 8) + t;
      int r = ci >> 3, cs = (ci & 7) ^ (r & 7);
      async16(&kp[(size_t)(k0 + r) * lds_ + hoff + (cs << 3)], &sK[ci << 3]);
    }
    // V regs -> sVt (perm-pack to V^T[d][k-quad], GEMM-style XOR layout)
    {
      const unsigned A0[4] = {va.x, va.y, va.z, va.w};
      const unsigned B0[4] = {vb_.x, vb_.y, vb_.z, vb_.w};
      const unsigned C0[4] = {vc.x, vc.y, vc.z, vc.w};
      const unsigned D0[4] = {vd.x, vd.y, vd.z, vd.w};
#pragma unroll
      for (int j = 0; j < 8; ++j) {
        const unsigned sel = (j & 1) ? 0x07060302u : 0x05040100u;
        ux2 wv;
        wv[0] = __builtin_amdgcn_perm(B0[j >> 1], A0[j >> 1], sel);
        wv[1] = __builtin_amdgcn_perm(D0[j >> 1], C0[j >> 1], sel);
        *(ux2*)&sVt[(vbrow + j) * 64 + ((kg7 ^ j) << 3) + k7o] = wv;
      }
    }
    __syncthreads();                 // drains asyncK + sVt writes

    // prefetch next V AFTER the barrier (not drained by it); hides under compute
    if (kt + 1 < 16) {
      const u16* vn = vbase + (size_t)(k0 + 128) * lds_;
      va = *(const uint4*)(vn);
      vb_ = *(const uint4*)(vn + (size_t)lds_);
      vc = *(const uint4*)(vn + 2 * (size_t)lds_);
      vd = *(const uint4*)(vn + 3 * (size_t)lds_);
    }

    // ---- QK^T swapped: lane holds S[q=lm][k=nt*16+lg*4+r] (raw scores) ----
    fx4 sc[8];
#pragma unroll
    for (int nt = 0; nt < 8; ++nt) sc[nt] = (fx4){0.f, 0.f, 0.f, 0.f};
    __builtin_amdgcn_s_setprio(1);
#pragma unroll
    for (int s = 0; s < 2; ++s) {
      const int g = (s << 2) + lg;
#pragma unroll
      for (int nt = 0; nt < 8; ++nt) {
        int rk = (nt << 4) + lm;
        sx8 bk = *(const sx8*)&sK[rk * 64 + ((g ^ (rk & 7)) << 3)];
        sc[nt] = __builtin_amdgcn_mfma_f32_16x16x32_bf16(bk, aq[s], sc[nt], 0, 0, 0);
      }
    }
    __builtin_amdgcn_s_setprio(0);

    if (!nomask) {
#pragma unroll
      for (int nt = 0; nt < 8; ++nt)
#pragma unroll
        for (int r = 0; r < 4; ++r) {
          const int col = k0 + (nt << 4) + (lg << 2) + r;
          if (mask[((size_t)myq << 11) + col] == 0) sc[nt][r] = -1e9f;
        }
    }

    float tm = sc[0][0];
#pragma unroll
    for (int nt = 0; nt < 8; ++nt)
#pragma unroll
      for (int r = 0; r < 4; ++r) tm = fmaxf(tm, sc[nt][r]);
    tm = fmaxf(tm, __shfl_xor(tm, 16));
    tm = fmaxf(tm, __shfl_xor(tm, 32));

    if (!__all(tm <= m_prev + RTHR)) {     // defer-max: rescale rarely
      const float mn = fmaxf(m_prev, tm);
      const float alpha = fexp2((m_prev - mn) * SCL);
      lsum *= alpha;
#pragma unroll
      for (int r = 0; r < 4; ++r) {
        float ar = __shfl(alpha, aslot + r);
#pragma unroll
        for (int ot = 0; ot < 4; ++ot) o[ot][r] *= ar;
      }
      m_prev = mn;
    }

    const float msc = m_prev * SCL;
    float rs = 0.f;
    float pvv[8][4];
#pragma unroll
    for (int nt = 0; nt < 8; ++nt)
#pragma unroll
      for (int r = 0; r < 4; ++r) {
        float e = fexp2(__builtin_fmaf(sc[nt][r], SCL, -msc));
        pvv[nt][r] = e;
        rs += e;
      }
    rs += __shfl_xor(rs, 16);
    rs += __shfl_xor(rs, 32);
    lsum += rs;

    // P -> bf16 pairs
    unsigned cpk[8][2];
#pragma unroll
    for (int nt = 0; nt < 8; ++nt) {
      asm("v_cvt_pk_bf16_f32 %0, %1, %2" : "=v"(cpk[nt][0]) : "v"(pvv[nt][0]), "v"(pvv[nt][1]));
      asm("v_cvt_pk_bf16_f32 %0, %1, %2" : "=v"(cpk[nt][1]) : "v"(pvv[nt][2]), "v"(pvv[nt][3]));
    }

    // all waves' QK^T sK reads are retired (consumed by MFMA) -> safe to
    // overwrite the aliased region. Raw barrier: no vmcnt drain, V-prefetch
    // stays in flight.
    __builtin_amdgcn_sched_barrier(0);
    __builtin_amdgcn_s_barrier();
    __builtin_amdgcn_sched_barrier(0);

    // P writes, wave-local swizzled (aliased onto sK region)
#pragma unroll
    for (int nt = 0; nt < 8; ++nt)
      *(ux2*)&pw[pwb + (((nt << 3) + (lg << 1)) ^ wswz)] = (ux2){cpk[nt][0], cpk[nt][1]};

    // PV: A-frag = P[q=lm][k=ks*32+lg*8+e]; B = sVt (XOR-granule layout)
    __builtin_amdgcn_s_setprio(1);
#pragma unroll
    for (int ks = 0; ks < 4; ++ks) {
      sx8 ap = *(const sx8*)&pw[pwb + (((ks << 4) + (lg << 2)) ^ wswz)];
      const int vrow = ((ks >> 1) << 6);
      const int vgr = (((ks & 1) << 2) + lg) ^ (lm & 7);
#pragma unroll
      for (int ot = 0; ot < 4; ++ot) {
        sx8 bv = *(const sx8*)&sVt[(vrow + (ot << 4) + lm) * 64 + (vgr << 3)];
        o[ot] = __builtin_amdgcn_mfma_f32_16x16x32_bf16(ap, bv, o[ot], 0, 0, 0);
      }
    }
    __builtin_amdgcn_s_setprio(0);
  }

  float inv = (lsum > 0.f) ? 1.f / lsum : 0.f;
#pragma unroll
  for (int r = 0; r < 4; ++r) {
    float ir = __shfl(inv, aslot + r);
#pragma unroll
    for (int ot = 0; ot < 4; ++ot) {
      const int rowg = q0 + (w << 4) + (lg << 2) + r;
      const int col = hoff + (ot << 4) + lm;
      ctx[((size_t)rowg << 10) + col] = f2b(o[ot][r] * ir);
    }
  }
}

// ---------------------------------------------------------------------------
// Dual LayerNorm, wave-per-row (4 rows/block): x = LN(a+res; g1,b1),
// xlo = LN(x; gf,bf). No LDS, no barriers; 64-lane shuffle reductions.
// ---------------------------------------------------------------------------
__global__ __launch_bounds__(256)
void ln_dual(const u16* __restrict__ a, const void* __restrict__ res, long roff,
             const void* __restrict__ g1, const void* __restrict__ b1,
             const void* __restrict__ gf, const void* __restrict__ bf,
             u16* __restrict__ xo, u16* __restrict__ xlo, const int* f_p) {
  const bool f = (*f_p != 0);
  const int t = threadIdx.x, lane = t & 63, w = t >> 6;
  const int row = (blockIdx.x << 2) + w;
  const size_t base = (size_t)row << 10;

  float v[16];
  float s = 0.f, ss = 0.f;
#pragma unroll
  for (int j = 0; j < 4; ++j) {
    const int c = (j << 8) + (lane << 2);
    ushx4 a4 = *(const ushx4*)(a + base + c);
    float rv[4];
    ld4f(res, roff + (long)base + c, f, rv);
#pragma unroll
    for (int q = 0; q < 4; ++q) {
      float x = b2f(a4[q]) + rv[q];
      v[(j << 2) + q] = x;
      s += x; ss += x * x;
    }
  }
#pragma unroll
  for (int off = 1; off < 64; off <<= 1) { s += __shfl_xor(s, off); ss += __shfl_xor(ss, off); }
  float mu = s * (1.f / 1024.f);
  float rstd = rsqrtf(fmaxf(ss * (1.f / 1024.f) - mu * mu, 0.f) + 1e-5f);

  float x16[16];
  float s2 = 0.f, ss2 = 0.f;
#pragma unroll
  for (int j = 0; j < 4; ++j) {
    const int c = (j << 8) + (lane << 2);
    float g4[4], b4[4];
    ld4f(g1, c, f, g4); ld4f(b1, c, f, b4);
    ushx4 xo4;
#pragma unroll
    for (int q = 0; q < 4; ++q) {
      float x = (v[(j << 2) + q] - mu) * rstd * g4[q] + b4[q];
      x16[(j << 2) + q] = x;
      xo4[q] = f2b(x);
      s2 += x; ss2 += x * x;
    }
    *(ushx4*)(xo + base + c) = xo4;
  }
#pragma unroll
  for (int off = 1; off < 64; off <<= 1) { s2 += __shfl_xor(s2, off); ss2 += __shfl_xor(ss2, off); }
  float mu2 = s2 * (1.f / 1024.f);
  float rstd2 = rsqrtf(fmaxf(ss2 * (1.f / 1024.f) - mu2 * mu2, 0.f) + 1e-5f);

#pragma unroll
  for (int j = 0; j < 4; ++j) {
    const int c = (j << 8) + (lane << 2);
    float g4[4], b4[4];
    ld4f(gf, c, f, g4); ld4f(bf, c, f, b4);
    ushx4 xl4;
#pragma unroll
    for (int q = 0; q < 4; ++q)
      xl4[q] = f2b((x16[(j << 2) + q] - mu2) * rstd2 * g4[q] + b4[q]);
    *(ushx4*)(xlo + base + c) = xl4;
  }
}

// ---------------------------------------------------------------------------
// Final LayerNorm, wave-per-row (4 rows/block): out = LN(a+resx; g,b).
// ---------------------------------------------------------------------------
__global__ __launch_bounds__(256)
void ln_final(const u16* __restrict__ a, const u16* __restrict__ resx,
              const void* __restrict__ g, const void* __restrict__ bb,
              void* __restrict__ out, long ooff, const int* f_p) {
  const bool f = (*f_p != 0);
  const int t = threadIdx.x, lane = t & 63, w = t >> 6;
  const int row = (blockIdx.x << 2) + w;
  const size_t base = (size_t)row << 10;

  float v[16];
  float s = 0.f, ss = 0.f;
#pragma unroll
  for (int j = 0; j < 4; ++j) {
    const int c = (j << 8) + (lane << 2);
    ushx4 a4 = *(const ushx4*)(a + base + c);
    ushx4 r4 = *(const ushx4*)(resx + base + c);
#pragma unroll
    for (int q = 0; q < 4; ++q) {
      float x = b2f(a4[q]) + b2f(r4[q]);
      v[(j << 2) + q] = x;
      s += x; ss += x * x;
    }
  }
#pragma unroll
  for (int off = 1; off < 64; off <<= 1) { s += __shfl_xor(s, off); ss += __shfl_xor(ss, off); }
  float mu = s * (1.f / 1024.f);
  float rstd = rsqrtf(fmaxf(ss * (1.f / 1024.f) - mu * mu, 0.f) + 1e-5f);

#pragma unroll
  for (int j = 0; j < 4; ++j) {
    const int c = (j << 8) + (lane << 2);
    float g4[4], b4[4];
    ld4f(g, c, f, g4); ld4f(bb, c, f, b4);
    if (f) {
      fx4 o4;
#pragma unroll
      for (int q = 0; q < 4; ++q) o4[q] = (v[(j << 2) + q] - mu) * rstd * g4[q] + b4[q];
      *(fx4*)((float*)out + ooff + base + c) = o4;
    } else {
      ushx4 o4;
#pragma unroll
      for (int q = 0; q < 4; ++q) o4[q] = f2b((v[(j << 2) + q] - mu) * rstd * g4[q] + b4[q]);
      *(ushx4*)((u16*)out + ooff + base + c) = o4;
    }
  }
}

// ---------------------------------------------------------------------------
extern "C" void kernel_launch(void* const* d_in, const int* in_sizes, int n_in,
                              void* d_out, int out_size, void* d_ws, size_t ws_size,
                              hipStream_t stream) {
  (void)in_sizes; (void)n_in; (void)out_size;
  const void* query = d_in[0];
  const void* keyi  = d_in[1];
  const void* value = d_in[2];
  const int*  mask  = (const int*)d_in[3];
  const void* Wq = d_in[4];
  const void* Wk = d_in[5];
  const void* Wv = d_in[6];
  const void* Wo = d_in[7];
  const void* bo = d_in[8];
  const void* g1 = d_in[9];
  const void* b1 = d_in[10];
  const void* g2 = d_in[11];
  const void* b2 = d_in[12];
  const void* gff = d_in[13];
  const void* bff = d_in[14];
  const void* W1 = d_in[15];
  const void* bf1 = d_in[16];
  const void* W2 = d_in[17];
  const void* bf2 = d_in[18];

  char* p = (char*)d_ws;
  int* flags = (int*)p;
  const int* F = flags;
  const int* Z = flags + 1;
  const int* M = flags + 2;
  dim3 blk(256);

  // footprint(CH) = 4096 + 24MiB (packed weights) + 7*CH*2048 bytes
  const size_t FIXED = 4096 + ((size_t)24 << 20);
  const size_t needC = FIXED + (size_t)8192 * 14336;   // ~142.6 MB
  const size_t needA = FIXED + (size_t)4096 * 14336;   // ~80.0 MB
  const size_t needB = FIXED + (size_t)2048 * 14336;   // ~52.0 MB

  if (ws_size >= needB) {
    // ------------------------- NEW PATH -------------------------
    const int CH = (ws_size >= needC) ? 8192 : (ws_size >= needA) ? 4096 : 2048;
    const int nch = 8192 / CH;

    u16* Wqkv  = (u16*)(p + 4096);                       // [3*1024,1024]
    u16* Wo_bf = Wqkv + (size_t)3 * DM * DM;             // [1024,1024]
    u16* W1T   = Wo_bf + (size_t)DM * DM;                // [4096,1024]
    u16* W2T   = W1T + (size_t)DFF * DM;                 // [1024,4096]
    u16* D0    = W2T + (size_t)DM * DFF;                 // in_bf / h
    u16* D1    = D0 + (size_t)3 * CH * DM;               // qkv / ao,x,xln
    u16* D2    = D1 + (size_t)3 * CH * DM;               // ctx / ff
    u16* qb = D0;
    u16* qkv = D1;
    u16* ao = D1, *x = D1 + (size_t)CH * DM, *xln = D1 + (size_t)2 * CH * DM;
    u16* h = D0;                                         // CH*4096 elems
    u16* ctx = D2, *ff = D2;

    detect_kernel<<<1, 64, 0, stream>>>(query, flags);
    mask_scan<<<dim3(8192), blk, 0, stream>>>(mask, flags);
    pack_w<<<dim3(2048), blk, 0, stream>>>(Wq, Wk, Wv, Wo, Wqkv, Wo_bf, F);
    transpose_any<<<dim3(DFF / 64, DM / 64), blk, 0, stream>>>(W1, W1T, DM, DFF, F);
    transpose_any<<<dim3(DM / 64, DFF / 64), blk, 0, stream>>>(W2, W2T, DFF, DM, F);

    for (int c = 0; c < nch; ++c) {
      const long off = (long)c * CH * DM;
      const long n = (long)CH * DM;
      conv_bf3<<<dim3((int)(n >> 11), 3), blk, 0, stream>>>(query, keyi, value, off, qb, n, F);

      // q/k/v projections co-dispatched: z in {0,1,2}
      gemm_bb<false, false, false><<<dim3((CH / 128) * 8, 3), blk, 0, stream>>>(
          qb, (long)CH * DM, Wqkv, (long)DM * DM, nullptr,
          qkv, 1024L, CH, DM, DM, 3072, Z);

      const int bpc = CH / SEQ, b0 = c * bpc;
      attn_kernel<<<dim3(512, bpc), blk, 0, stream>>>(
          qkv, qkv + 1024, qkv + 2048, 3072,
          mask + (size_t)b0 * SEQ * SEQ, ctx, M);

      gemm_bb<false, true, true><<<dim3((CH / 128) * 8, 1), blk, 0, stream>>>(
          ctx, 0, Wo_bf, 0, bo, ao, 0, CH, DM, DM, DM, F);

      ln_dual<<<dim3(CH >> 2), blk, 0, stream>>>(ao, query, off, g1, b1, gff, bff, x, xln, F);

      gemm_bb<true, true, false><<<dim3((CH / 128) * 32, 1), blk, 0, stream>>>(
          xln, 0, W1T, 0, bf1, h, 0, CH, DFF, DM, DFF, F);
      gemm_bb<false, true, true><<<dim3((CH / 128) * 8, 1), blk, 0, stream>>>(
          h, 0, W2T, 0, bf2, ff, 0, CH, DM, DFF, DM, F);

      ln_final<<<dim3(CH >> 2), blk, 0, stream>>>(ff, x, g2, b2, d_out, off, F);
    }
  } else {
    // ------------------------- LEGACY PATH (round-3 proven) -------------------------
    const int CH = 2048, FH = 1024;
    const int nch = 8192 / CH;
    const size_t h0 = 4096;
    u16* W1T = (u16*)(p + h0);
    u16* W2T = W1T + (size_t)DFF * DM;
    u16* hb  = (u16*)(p + h0 + ((size_t)16 << 20));
    const size_t HB = (size_t)FH * DFF * 2;
    u16* r0 = (u16*)(p + h0 + ((size_t)16 << 20) + HB);
    const size_t CE = (size_t)CH * DM;
    u16* qp = r0;
    u16* kp = qp + CE;
    u16* vp = kp + CE;
    u16* ctxb = vp + CE;
    u16* x = qp; u16* xln = kp; u16* ao = vp; u16* ff = ctxb;

    detect_kernel<<<1, 64, 0, stream>>>(query, flags);
    mask_scan<<<dim3(8192), blk, 0, stream>>>(mask, flags);
    transpose_any<<<dim3(DFF / 64, DM / 64), blk, 0, stream>>>(W1, W1T, DM, DFF, F);
    transpose_any<<<dim3(DM / 64, DFF / 64), blk, 0, stream>>>(W2, W2T, DFF, DM, F);

    for (int c = 0; c < nch; ++c) {
      const long off = (long)c * CH * DM;
      dim3 gq((CH / 128) * (DM / 128));

      gemm_nt<false, false><<<gq, blk, 0, stream>>>(query, off, Wq, Wq, qp, CH, DM, DM, F, F, Z);
      gemm_nt<false, false><<<gq, blk, 0, stream>>>(keyi,  off, Wk, Wk, kp, CH, DM, DM, F, F, Z);
      gemm_nt<false, false><<<gq, blk, 0, stream>>>(value, off, Wv, Wv, vp, CH, DM, DM, F, F, Z);

      const int bpc = CH / SEQ, b0 = c * bpc;
      for (int bl = 0; bl < bpc; ++bl) {
        const size_t lo = (size_t)bl * SEQ * DM;
        attn_kernel<<<dim3(512, 1), blk, 0, stream>>>(
            qp + lo, kp + lo, vp + lo, 1024,
            mask + (size_t)(b0 + bl) * SEQ * SEQ, ctxb + lo, M);
      }

      gemm_nt<false, true><<<gq, blk, 0, stream>>>(ctxb, 0, Wo, bo, ao, CH, DM, DM, Z, F, F);

      ln_dual<<<dim3(CH >> 2), blk, 0, stream>>>(ao, query, off, g1, b1, gff, bff, x, xln, F);

      for (int qs = 0; qs < CH / FH; ++qs) {
        const long so = (long)qs * FH * DM;
        gemm_nt<true, true><<<dim3((FH / 128) * (DFF / 128)), blk, 0, stream>>>(
            xln + so, 0, W1T, bf1, hb, FH, DFF, DM, Z, Z, F);
        gemm_nt<false, true><<<dim3((FH / 128) * (DM / 128)), blk, 0, stream>>>(
            hb, 0, W2T, bf2, ff + so, FH, DM, DFF, Z, Z, F);
      }

      ln_final<<<dim3(CH >> 2), blk, 0, stream>>>(ff, x, g2, b2, d_out, off, F);
    }
  }
}

// Round 7
// 657.403 us; speedup vs baseline: 1.0168x; 1.0168x over previous
//
#include <hip/hip_runtime.h>

// ---------------------------------------------------------------------------
// SublayerConnection: MHA + residual/LN + FF + residual/LN
// B=4 S=2048 D=1024 H=16 Dk=64 Dff=4096.
// Round 11: (1) LN kernels reverted to round-9 block-per-row (wave-per-row
// cost +35us — evidence: r10 total regressed while attn improved).
// (2) attn row-sum moved VALU->MFMA: osum = mfma(P, ones, osum), same
// C-layout rows as o -> final normalize shuffle-free; removes 32 adds +
// 2 shfls per tile from the 40%-busy VALU pipe. attn stays (256,3).
// GEMMs (round-9 DBUF, proven) untouched.
// ---------------------------------------------------------------------------

#define DM   1024
#define DFF  4096
#define SEQ  2048

typedef unsigned short u16;
typedef short          sx8  __attribute__((ext_vector_type(8)));
typedef unsigned short ushx8 __attribute__((ext_vector_type(8)));
typedef unsigned short ushx4 __attribute__((ext_vector_type(4)));
typedef float          fx4  __attribute__((ext_vector_type(4)));
typedef unsigned int   ux2  __attribute__((ext_vector_type(2)));

__device__ __forceinline__ void async16(const void* g, void* l) {
  __builtin_amdgcn_global_load_lds((__attribute__((address_space(1))) void*)g,
                                   (__attribute__((address_space(3))) void*)l,
                                   16, 0, 0);
}
__device__ __forceinline__ float b2f(u16 u) {
  union { unsigned int i; float f; } v; v.i = ((unsigned int)u) << 16; return v.f;
}
__device__ __forceinline__ u16 f2b(float f) {
  union { float f; unsigned int i; } v; v.f = f;
  unsigned int r = v.i + 0x7fffu + ((v.i >> 16) & 1u);
  return (u16)(r >> 16);
}
__device__ __forceinline__ float fexp2(float x) {
#if __has_builtin(__builtin_amdgcn_exp2f)
  return __builtin_amdgcn_exp2f(x);
#else
  return exp2f(x);
#endif
}
__device__ __forceinline__ ushx8 ld8(const void* p, long idx, bool f32) {
  if (f32) {
    const float* s = (const float*)p + idx;
    fx4 a = *(const fx4*)s, b = *(const fx4*)(s + 4);
    ushx8 r;
    r[0] = f2b(a[0]); r[1] = f2b(a[1]); r[2] = f2b(a[2]); r[3] = f2b(a[3]);
    r[4] = f2b(b[0]); r[5] = f2b(b[1]); r[6] = f2b(b[2]); r[7] = f2b(b[3]);
    return r;
  }
  return *(const ushx8*)((const u16*)p + idx);
}
__device__ __forceinline__ void ld4f(const void* p, long idx, bool f32, float* o) {
  if (f32) {
    fx4 a = *(const fx4*)((const float*)p + idx);
    o[0] = a[0]; o[1] = a[1]; o[2] = a[2]; o[3] = a[3];
  } else {
    ushx4 a = *(const ushx4*)((const u16*)p + idx);
    o[0] = b2f(a[0]); o[1] = b2f(a[1]); o[2] = b2f(a[2]); o[3] = b2f(a[3]);
  }
}

// ---------------------------------------------------------------------------
__global__ void detect_kernel(const void* q, int* flags) {
  int lane = threadIdx.x;
  u16 v = ((const u16*)q)[lane << 1];
  int e = (v >> 7) & 0xff;
  int pl = (e >= 0x60 && e <= 0x8c) ? 1 : 0;
  unsigned long long m = __ballot(pl);
  if (lane == 0) { flags[0] = (__popcll(m) >= 40) ? 0 : 1; flags[1] = 0; flags[2] = 1; }
}

// Scan mask for any zero; flags[2] stays 1 iff every element nonzero.
__global__ __launch_bounds__(256)
void mask_scan(const int* __restrict__ m, int* flags) {
  long i = (((long)blockIdx.x << 8) + threadIdx.x) << 3;
  const int4 a = *(const int4*)(m + i);
  const int4 b = *(const int4*)(m + i + 4);
  bool ok = a.x && a.y && a.z && a.w && b.x && b.y && b.z && b.w;
  if (!__all(ok)) { if ((threadIdx.x & 63) == 0) flags[2] = 0; }
}

// Pack Wq/Wk/Wv -> Wqkv [3*1024,1024] bf16 and Wo -> bf16.
__global__ __launch_bounds__(256)
void pack_w(const void* Wq, const void* Wk, const void* Wv, const void* Wo,
            u16* Wqkv, u16* Wo_bf, const int* f_p) {
  const bool f = (*f_p != 0);
  long i = (((long)blockIdx.x << 8) + threadIdx.x) << 3;
  const long QKVN = (long)3 * DM * DM;
  if (i < QKVN) {
    int row = (int)(i >> 10);
    const void* src = (row < DM) ? Wq : (row < 2 * DM ? Wk : Wv);
    long s = ((long)(row & (DM - 1)) << 10) + (i & 1023);
    *(ushx8*)(Wqkv + i) = ld8(src, s, f);
  } else {
    long j = i - QKVN;
    *(ushx8*)(Wo_bf + j) = ld8(Wo, j, f);
  }
}

// Convert q/k/v chunk to bf16; grid.y selects source, dst stride n.
__global__ __launch_bounds__(256)
void conv_bf3(const void* q, const void* k, const void* v, long off,
              u16* dst, long n, const int* f_p) {
  const bool f = (*f_p != 0);
  const void* src = (blockIdx.y == 0) ? q : (blockIdx.y == 1 ? k : v);
  long i = (((long)blockIdx.x << 8) + threadIdx.x) << 3;
  if (i < n) *(ushx8*)(dst + (long)blockIdx.y * n + i) = ld8(src, off + i, f);
}

// ---------------------------------------------------------------------------
// Pure-bf16 NT GEMM with global_load_lds(16B) staging. C=A@B^T (+bias)(+relu).
// grid.y = z selects (A,B,C) via element strides az/bz/cz. C row stride ldc.
// DBUF: 2 LDS buffers (64KB -> 2 blocks/CU), prefetch-next then vmcnt(8)
// BEFORE the pre-compute raw barrier (cross-wave sound); prefetch spans
// the compute. All grids %8==0 -> bijective XCD swizzle.
// ---------------------------------------------------------------------------
template<bool RELU, bool BIAS, bool DBUF>
__global__ __launch_bounds__(256)
void gemm_bb(const u16* __restrict__ A, long az, const u16* __restrict__ B, long bz,
             const void* __restrict__ bias, u16* __restrict__ C, long cz,
             int M, int N, int K, int ldc, const int* biasf_p) {
  __shared__ __align__(16) u16 sA[(DBUF ? 2 : 1) * 128 * 64];
  __shared__ __align__(16) u16 sB[(DBUF ? 2 : 1) * 128 * 64];
  const int z = blockIdx.y;
  A += (long)z * az; B += (long)z * bz; C += (long)z * cz;
  const bool biasf = BIAS && (*biasf_p != 0);
  const int t = threadIdx.x;
  const int lane = t & 63, w = t >> 6;
  const int lm = lane & 15, lg = lane >> 4;
  const int ntil = N >> 7;
  // XCD-aware bijective swizzle (gridDim.x % 8 == 0 for all dispatches)
  const int bx = (blockIdx.x & 7) * ((int)gridDim.x >> 3) + (blockIdx.x >> 3);
  const int m0 = (bx / ntil) << 7;
  const int n0 = (bx % ntil) << 7;
  const int wm = (w & 1) << 6, wn = (w >> 1) << 6;

  fx4 acc[4][4];
#pragma unroll
  for (int i = 0; i < 4; ++i)
#pragma unroll
    for (int j = 0; j < 4; ++j) acc[i][j] = (fx4){0.f, 0.f, 0.f, 0.f};

  auto stage = [&](int so, int kt) {
#pragma unroll
    for (int it = 0; it < 4; ++it) {
      int ci = (it << 8) + t;
      int r = ci >> 3, cs = (ci & 7) ^ (r & 7);
      async16(&A[(size_t)(m0 + r) * K + kt + (cs << 3)], &sA[so + (ci << 3)]);
    }
#pragma unroll
    for (int it = 0; it < 4; ++it) {
      int ci = (it << 8) + t;
      int r = ci >> 3, cs = (ci & 7) ^ (r & 7);
      async16(&B[(size_t)(n0 + r) * K + kt + (cs << 3)], &sB[so + (ci << 3)]);
    }
  };

  auto compute = [&](int so) {
#pragma unroll
    for (int s = 0; s < 2; ++s) {
      const int g = (s << 2) + lg;
      sx8 afr[4], bfr[4];
#pragma unroll
      for (int i = 0; i < 4; ++i) {
        int ra = wm + (i << 4) + lm;
        afr[i] = *(const sx8*)&sA[so + ra * 64 + ((g ^ (ra & 7)) << 3)];
        int rb = wn + (i << 4) + lm;
        bfr[i] = *(const sx8*)&sB[so + rb * 64 + ((g ^ (rb & 7)) << 3)];
      }
      __builtin_amdgcn_s_setprio(1);
#pragma unroll
      for (int i = 0; i < 4; ++i)
#pragma unroll
        for (int j = 0; j < 4; ++j)
          acc[i][j] = __builtin_amdgcn_mfma_f32_16x16x32_bf16(afr[i], bfr[j], acc[i][j], 0, 0, 0);
      __builtin_amdgcn_s_setprio(0);
    }
  };

  if (DBUF) {
    const int NT = K >> 6;
    stage(0, 0);
    for (int n = 0; n < NT; ++n) {
      if (n + 1 < NT) {
        stage(((n + 1) & 1) << 13, (n + 1) << 6);   // prefetch next tile
        asm volatile("s_waitcnt vmcnt(8)" ::: "memory");  // own tile-n landed
      } else {
        asm volatile("s_waitcnt vmcnt(0)" ::: "memory");
      }
      __builtin_amdgcn_s_barrier();                 // all waves' tile-n landed
      __builtin_amdgcn_sched_barrier(0);
      compute((n & 1) << 13);
      if (n + 1 < NT) __builtin_amdgcn_s_barrier(); // buf free before restage
    }
  } else {
    for (int kt = 0; kt < K; kt += 64) {
      __syncthreads();
      stage(0, kt);
      __syncthreads();
      compute(0);
    }
  }

#pragma unroll
  for (int j = 0; j < 4; ++j) {
    const int col = n0 + wn + (j << 4) + lm;
    float bv = 0.f;
    if (BIAS) bv = biasf ? ((const float*)bias)[col] : b2f(((const u16*)bias)[col]);
#pragma unroll
    for (int i = 0; i < 4; ++i) {
      const int row0 = m0 + wm + (i << 4) + (lg << 2);
#pragma unroll
      for (int r = 0; r < 4; ++r) {
        float v = acc[i][j][r] + bv;
        if (RELU) v = fmaxf(v, 0.f);
        C[(size_t)(row0 + r) * ldc + col] = f2b(v);
      }
    }
  }
}

// ---------------------------------------------------------------------------
// Flag-dtype NT GEMM (legacy path, proven in round 3).
// ---------------------------------------------------------------------------
template<bool RELU, bool BIAS>
__global__ __launch_bounds__(256)
void gemm_nt(const void* __restrict__ A, long aoff, const void* __restrict__ Bm,
             const void* __restrict__ bias, u16* __restrict__ C,
             int M, int N, int K,
             const int* af_p, const int* bf_p, const int* biasf_p) {
  __shared__ __align__(16) u16 sA[128 * 64];
  __shared__ __align__(16) u16 sB[128 * 64];
  const bool af = (*af_p != 0), bfl = (*bf_p != 0), biasf = (*biasf_p != 0);
  const int t = threadIdx.x;
  const int lane = t & 63, w = t >> 6;
  const int lm = lane & 15, lg = lane >> 4;
  const int ntil = N >> 7;
  const int m0 = (blockIdx.x / ntil) << 7;
  const int n0 = (blockIdx.x % ntil) << 7;
  const int wm = (w & 1) << 6, wn = (w >> 1) << 6;

  fx4 acc[4][4];
#pragma unroll
  for (int i = 0; i < 4; ++i)
#pragma unroll
    for (int j = 0; j < 4; ++j) acc[i][j] = (fx4){0.f, 0.f, 0.f, 0.f};

  for (int kt = 0; kt < K; kt += 64) {
    __syncthreads();
#pragma unroll
    for (int it = 0; it < 4; ++it) {
      int ci = (it << 8) + t;
      int r = ci >> 3, cs = (ci & 7) ^ (r & 7);
      ushx8 va = ld8(A, aoff + (long)(m0 + r) * K + kt + (cs << 3), af);
      *(ushx8*)&sA[ci << 3] = va;
      ushx8 vb = ld8(Bm, (long)(n0 + r) * K + kt + (cs << 3), bfl);
      *(ushx8*)&sB[ci << 3] = vb;
    }
    __syncthreads();
#pragma unroll
    for (int s = 0; s < 2; ++s) {
      const int g = (s << 2) + lg;
      sx8 afr[4], bfr[4];
#pragma unroll
      for (int i = 0; i < 4; ++i) {
        int ra = wm + (i << 4) + lm;
        afr[i] = *(const sx8*)&sA[ra * 64 + ((g ^ (ra & 7)) << 3)];
        int rb = wn + (i << 4) + lm;
        bfr[i] = *(const sx8*)&sB[rb * 64 + ((g ^ (rb & 7)) << 3)];
      }
#pragma unroll
      for (int i = 0; i < 4; ++i)
#pragma unroll
        for (int j = 0; j < 4; ++j)
          acc[i][j] = __builtin_amdgcn_mfma_f32_16x16x32_bf16(afr[i], bfr[j], acc[i][j], 0, 0, 0);
    }
  }

#pragma unroll
  for (int j = 0; j < 4; ++j) {
    const int col = n0 + wn + (j << 4) + lm;
    float bv = 0.f;
    if (BIAS) bv = biasf ? ((const float*)bias)[col] : b2f(((const u16*)bias)[col]);
#pragma unroll
    for (int i = 0; i < 4; ++i) {
      const int row0 = m0 + wm + (i << 4) + (lg << 2);
#pragma unroll
      for (int r = 0; r < 4; ++r) {
        float v = acc[i][j][r] + bv;
        if (RELU) v = fmaxf(v, 0.f);
        C[(size_t)(row0 + r) * N + col] = f2b(v);
      }
    }
  }
}

// ---------------------------------------------------------------------------
__global__ __launch_bounds__(256)
void transpose_any(const void* __restrict__ in, u16* __restrict__ out,
                   int R, int C, const int* f_p) {
  __shared__ u16 tile[64][68];
  const bool f = (*f_p != 0);
  const int r0 = blockIdx.y << 6, c0 = blockIdx.x << 6;
  const int t = threadIdx.x;
#pragma unroll
  for (int it = 0; it < 4; ++it) {
    int j = (it << 8) + t;
    int rr = j >> 4, cc4 = (j & 15) << 2;
    float v[4];
    ld4f(in, (long)(r0 + rr) * C + c0 + cc4, f, v);
#pragma unroll
    for (int q = 0; q < 4; ++q) tile[rr][cc4 + q] = f2b(v[q]);
  }
  __syncthreads();
#pragma unroll
  for (int it = 0; it < 4; ++it) {
    int j = (it << 8) + t;
    int cc = j >> 4, rr4 = (j & 15) << 2;
    ushx4 v;
    v[0] = tile[rr4 + 0][cc]; v[1] = tile[rr4 + 1][cc];
    v[2] = tile[rr4 + 2][cc]; v[3] = tile[rr4 + 3][cc];
    *(ushx4*)&out[(size_t)(c0 + cc) * R + r0 + rr4] = v;
  }
}

// ---------------------------------------------------------------------------
// Flash attention, swapped-QK^T. grid.x = 512 (XCD-swizzled); grid.y = batch.
// Per wave 16 q rows; lane (lm,lg) owns softmax row q=lm for k=nt*16+lg*4+r.
// K via global_load_lds. V prefetched in 4 NAMED uint4 regs. sVt in GEMM-
// style [128][64] XOR-granule layout (0-conflict PV reads). P LDS aliases
// sK. Row-sum via MFMA: osum = mfma(P, ones, osum) -- same C-layout rows
// as o, so the final normalize is shuffle-free and the 32-add VALU row-sum
// is gone. LDS = 32KB, launch_bounds (256,3) (proven no-spill).
// ---------------------------------------------------------------------------
__global__ __launch_bounds__(256, 3)
void attn_kernel(const u16* __restrict__ qp, const u16* __restrict__ kp,
                 const u16* __restrict__ vp, int lds_,
                 const int* __restrict__ mask, u16* __restrict__ ctx,
                 const int* __restrict__ mflag) {
  __shared__ __align__(16) u16 smem[16384];   // 32KB: sK(16K)|sVt(16K); sP aliases sK
  u16* const sK  = smem;
  u16* const sVt = smem + 8192;
  unsigned* const sPal = (unsigned*)smem;

  const bool nomask = (*mflag != 0);
  const long boff = (long)blockIdx.y * SEQ * (long)lds_;
  qp += boff; kp += boff; vp += boff;
  mask += (size_t)blockIdx.y * ((size_t)SEQ * SEQ);
  ctx += (size_t)blockIdx.y * ((size_t)SEQ * DM);

  const int id = (blockIdx.x & 7) * ((int)gridDim.x >> 3) + (blockIdx.x >> 3);
  const int q0 = (id & 31) << 6;
  const int h  = id >> 5;
  const int t = threadIdx.x, lane = t & 63, w = t >> 6;
  const int hoff = h << 6;
  const int lm = lane & 15, lg = lane >> 4;
  const int myq = q0 + (w << 4) + lm;        // this lane's softmax row
  const int aslot = 20 * lg;                  // shfl src: lane lg*16 + (lg*4+r)

  // staging geometry
  const int kq = (t & 31) << 2, dg = (t >> 5) << 3;
  const int kg7 = (kq >> 3) & 7;              // thread's k-quad granule
  const int k7o = kq & 7;                     // offset within granule (0 or 4)
  const int vbrow = ((kq >> 6) << 6) + dg;    // sVt base row for writes
  unsigned* pw = sPal + (w << 10);
  const int wswz = (lm & 7) << 2;
  const int pwb = lm << 6;

  // all-ones bf16 B-fragment for the row-sum MFMA
  sx8 one_b;
#pragma unroll
  for (int j = 0; j < 8; ++j) one_b[j] = (short)0x3F80;

  // Q fragments: row myq, octets lg and 4+lg
  sx8 aq[2];
#pragma unroll
  for (int s = 0; s < 2; ++s)
    aq[s] = *(const sx8*)&qp[(size_t)myq * lds_ + hoff + (((s << 2) + lg) << 3)];

  fx4 o[4];
#pragma unroll
  for (int i = 0; i < 4; ++i) o[i] = (fx4){0.f, 0.f, 0.f, 0.f};
  fx4 osum = (fx4){0.f, 0.f, 0.f, 0.f};
  float m_prev = -1e30f;
  const float SCL = 0.18033688f;    // 0.125 * log2(e)
  const float RTHR = 44.36142f;     // 8 / SCL (defer-max bound, raw domain)

  // V prefetch (tile 0) in NAMED registers
  const u16* vbase = vp + (size_t)kq * lds_ + hoff + dg;
  uint4 va = *(const uint4*)(vbase);
  uint4 vb_ = *(const uint4*)(vbase + (size_t)lds_);
  uint4 vc = *(const uint4*)(vbase + 2 * (size_t)lds_);
  uint4 vd = *(const uint4*)(vbase + 3 * (size_t)lds_);

  for (int kt = 0; kt < 16; ++kt) {
    const int k0 = kt << 7;
    __syncthreads();                 // prev compute done; LDS reusable
    // K -> sK via global_load_lds (swizzled source, linear LDS)
#pragma unroll
    for (int it = 0; it < 4; ++it) {
      int ci = (it << 8) + t;
      int r = ci >> 3, cs = (ci & 7) ^ (r & 7);
      async16(&kp[(size_t)(k0 + r) * lds_ + hoff + (cs << 3)], &sK[ci << 3]);
    }
    // V regs -> sVt (perm-pack to V^T[d][k-quad], GEMM-style XOR layout)
    {
      const unsigned A0[4] = {va.x, va.y, va.z, va.w};
      const unsigned B0[4] = {vb_.x, vb_.y, vb_.z, vb_.w};
      const unsigned C0[4] = {vc.x, vc.y, vc.z, vc.w};
      const unsigned D0[4] = {vd.x, vd.y, vd.z, vd.w};
#pragma unroll
      for (int j = 0; j < 8; ++j) {
        const unsigned sel = (j & 1) ? 0x07060302u : 0x05040100u;
        ux2 wv;
        wv[0] = __builtin_amdgcn_perm(B0[j >> 1], A0[j >> 1], sel);
        wv[1] = __builtin_amdgcn_perm(D0[j >> 1], C0[j >> 1], sel);
        *(ux2*)&sVt[(vbrow + j) * 64 + ((kg7 ^ j) << 3) + k7o] = wv;
      }
    }
    __syncthreads();                 // drains asyncK + sVt writes

    // prefetch next V AFTER the barrier (not drained by it); hides under compute
    if (kt + 1 < 16) {
      const u16* vn = vbase + (size_t)(k0 + 128) * lds_;
      va = *(const uint4*)(vn);
      vb_ = *(const uint4*)(vn + (size_t)lds_);
      vc = *(const uint4*)(vn + 2 * (size_t)lds_);
      vd = *(const uint4*)(vn + 3 * (size_t)lds_);
    }

    // ---- QK^T swapped: lane holds S[q=lm][k=nt*16+lg*4+r] (raw scores) ----
    fx4 sc[8];
#pragma unroll
    for (int nt = 0; nt < 8; ++nt) sc[nt] = (fx4){0.f, 0.f, 0.f, 0.f};
    __builtin_amdgcn_s_setprio(1);
#pragma unroll
    for (int s = 0; s < 2; ++s) {
      const int g = (s << 2) + lg;
#pragma unroll
      for (int nt = 0; nt < 8; ++nt) {
        int rk = (nt << 4) + lm;
        sx8 bk = *(const sx8*)&sK[rk * 64 + ((g ^ (rk & 7)) << 3)];
        sc[nt] = __builtin_amdgcn_mfma_f32_16x16x32_bf16(bk, aq[s], sc[nt], 0, 0, 0);
      }
    }
    __builtin_amdgcn_s_setprio(0);

    if (!nomask) {
#pragma unroll
      for (int nt = 0; nt < 8; ++nt)
#pragma unroll
        for (int r = 0; r < 4; ++r) {
          const int col = k0 + (nt << 4) + (lg << 2) + r;
          if (mask[((size_t)myq << 11) + col] == 0) sc[nt][r] = -1e9f;
        }
    }

    float tm = sc[0][0];
#pragma unroll
    for (int nt = 0; nt < 8; ++nt)
#pragma unroll
      for (int r = 0; r < 4; ++r) tm = fmaxf(tm, sc[nt][r]);
    tm = fmaxf(tm, __shfl_xor(tm, 16));
    tm = fmaxf(tm, __shfl_xor(tm, 32));

    if (!__all(tm <= m_prev + RTHR)) {     // defer-max: rescale rarely
      const float mn = fmaxf(m_prev, tm);
      const float alpha = fexp2((m_prev - mn) * SCL);
#pragma unroll
      for (int r = 0; r < 4; ++r) {
        float ar = __shfl(alpha, aslot + r);
#pragma unroll
        for (int ot = 0; ot < 4; ++ot) o[ot][r] *= ar;
        osum[r] *= ar;
      }
      m_prev = mn;
    }

    const float msc = m_prev * SCL;
    float pvv[8][4];
#pragma unroll
    for (int nt = 0; nt < 8; ++nt)
#pragma unroll
      for (int r = 0; r < 4; ++r)
        pvv[nt][r] = fexp2(__builtin_fmaf(sc[nt][r], SCL, -msc));

    // P -> bf16 pairs
    unsigned cpk[8][2];
#pragma unroll
    for (int nt = 0; nt < 8; ++nt) {
      asm("v_cvt_pk_bf16_f32 %0, %1, %2" : "=v"(cpk[nt][0]) : "v"(pvv[nt][0]), "v"(pvv[nt][1]));
      asm("v_cvt_pk_bf16_f32 %0, %1, %2" : "=v"(cpk[nt][1]) : "v"(pvv[nt][2]), "v"(pvv[nt][3]));
    }

    // all waves' QK^T sK reads are retired (consumed by MFMA) -> safe to
    // overwrite the aliased region. Raw barrier: no vmcnt drain, V-prefetch
    // stays in flight.
    __builtin_amdgcn_sched_barrier(0);
    __builtin_amdgcn_s_barrier();
    __builtin_amdgcn_sched_barrier(0);

    // P writes, wave-local swizzled (aliased onto sK region)
#pragma unroll
    for (int nt = 0; nt < 8; ++nt)
      *(ux2*)&pw[pwb + (((nt << 3) + (lg << 1)) ^ wswz)] = (ux2){cpk[nt][0], cpk[nt][1]};

    // PV: A-frag = P[q=lm][k=ks*32+lg*8+e]; B = sVt (XOR-granule layout).
    // Row-sum rides the matrix pipe: osum = mfma(P, ones, osum).
    __builtin_amdgcn_s_setprio(1);
#pragma unroll
    for (int ks = 0; ks < 4; ++ks) {
      sx8 ap = *(const sx8*)&pw[pwb + (((ks << 4) + (lg << 2)) ^ wswz)];
      const int vrow = ((ks >> 1) << 6);
      const int vgr = (((ks & 1) << 2) + lg) ^ (lm & 7);
#pragma unroll
      for (int ot = 0; ot < 4; ++ot) {
        sx8 bv = *(const sx8*)&sVt[(vrow + (ot << 4) + lm) * 64 + (vgr << 3)];
        o[ot] = __builtin_amdgcn_mfma_f32_16x16x32_bf16(ap, bv, o[ot], 0, 0, 0);
      }
      osum = __builtin_amdgcn_mfma_f32_16x16x32_bf16(ap, one_b, osum, 0, 0, 0);
    }
    __builtin_amdgcn_s_setprio(0);
  }

  // osum rows == o rows (same A-fragment, same C-layout): shuffle-free.
#pragma unroll
  for (int r = 0; r < 4; ++r) {
    const float ir = (osum[r] > 0.f) ? 1.f / osum[r] : 0.f;
#pragma unroll
    for (int ot = 0; ot < 4; ++ot) {
      const int rowg = q0 + (w << 4) + (lg << 2) + r;
      const int col = hoff + (ot << 4) + lm;
      ctx[((size_t)rowg << 10) + col] = f2b(o[ot][r] * ir);
    }
  }
}

// ---------------------------------------------------------------------------
__global__ __launch_bounds__(256)
void ln_dual(const u16* __restrict__ a, const void* __restrict__ res, long roff,
             const void* __restrict__ g1, const void* __restrict__ b1,
             const void* __restrict__ gf, const void* __restrict__ bf,
             u16* __restrict__ xo, u16* __restrict__ xlo, const int* f_p) {
  __shared__ float red[8];
  const bool f = (*f_p != 0);
  const int row = blockIdx.x, t = threadIdx.x;
  const int lane = t & 63, w = t >> 6;
  const size_t base = (size_t)row << 10;
  const int c = t << 2;

  ushx4 a4 = *(const ushx4*)(a + base + c);
  float rv[4];
  ld4f(res, roff + (long)base + c, f, rv);
  float v[4], s = 0.f, ss = 0.f;
#pragma unroll
  for (int j = 0; j < 4; ++j) { v[j] = b2f(a4[j]) + rv[j]; s += v[j]; ss += v[j] * v[j]; }
#pragma unroll
  for (int off = 32; off > 0; off >>= 1) { s += __shfl_xor(s, off); ss += __shfl_xor(ss, off); }
  if (lane == 0) { red[w] = s; red[4 + w] = ss; }
  __syncthreads();
  s = red[0] + red[1] + red[2] + red[3];
  ss = red[4] + red[5] + red[6] + red[7];
  float mu = s * (1.f / 1024.f);
  float rstd = rsqrtf(fmaxf(ss * (1.f / 1024.f) - mu * mu, 0.f) + 1e-5f);

  float g4[4], b4[4];
  ld4f(g1, c, f, g4); ld4f(b1, c, f, b4);
  float x[4], s2 = 0.f, ss2 = 0.f;
  ushx4 xo4;
#pragma unroll
  for (int j = 0; j < 4; ++j) {
    x[j] = (v[j] - mu) * rstd * g4[j] + b4[j];
    xo4[j] = f2b(x[j]);
    s2 += x[j]; ss2 += x[j] * x[j];
  }
  *(ushx4*)(xo + base + c) = xo4;
#pragma unroll
  for (int off = 32; off > 0; off >>= 1) { s2 += __shfl_xor(s2, off); ss2 += __shfl_xor(ss2, off); }
  __syncthreads();
  if (lane == 0) { red[w] = s2; red[4 + w] = ss2; }
  __syncthreads();
  s2 = red[0] + red[1] + red[2] + red[3];
  ss2 = red[4] + red[5] + red[6] + red[7];
  float mu2 = s2 * (1.f / 1024.f);
  float rstd2 = rsqrtf(fmaxf(ss2 * (1.f / 1024.f) - mu2 * mu2, 0.f) + 1e-5f);

  ld4f(gf, c, f, g4); ld4f(bf, c, f, b4);
  ushx4 xl4;
#pragma unroll
  for (int j = 0; j < 4; ++j)
    xl4[j] = f2b((x[j] - mu2) * rstd2 * g4[j] + b4[j]);
  *(ushx4*)(xlo + base + c) = xl4;
}

// ---------------------------------------------------------------------------
__global__ __launch_bounds__(256)
void ln_final(const u16* __restrict__ a, const u16* __restrict__ resx,
              const void* __restrict__ g, const void* __restrict__ bb,
              void* __restrict__ out, long ooff, const int* f_p) {
  __shared__ float red[8];
  const bool f = (*f_p != 0);
  const int row = blockIdx.x, t = threadIdx.x;
  const int lane = t & 63, w = t >> 6;
  const size_t base = (size_t)row << 10;
  const int c = t << 2;

  ushx4 a4 = *(const ushx4*)(a + base + c);
  ushx4 r4 = *(const ushx4*)(resx + base + c);
  float v[4], s = 0.f, ss = 0.f;
#pragma unroll
  for (int j = 0; j < 4; ++j) { v[j] = b2f(a4[j]) + b2f(r4[j]); s += v[j]; ss += v[j] * v[j]; }
#pragma unroll
  for (int off = 32; off > 0; off >>= 1) { s += __shfl_xor(s, off); ss += __shfl_xor(ss, off); }
  if (lane == 0) { red[w] = s; red[4 + w] = ss; }
  __syncthreads();
  s = red[0] + red[1] + red[2] + red[3];
  ss = red[4] + red[5] + red[6] + red[7];
  float mu = s * (1.f / 1024.f);
  float rstd = rsqrtf(fmaxf(ss * (1.f / 1024.f) - mu * mu, 0.f) + 1e-5f);

  float g4[4], b4[4];
  ld4f(g, c, f, g4); ld4f(bb, c, f, b4);
  if (f) {
    fx4 o4;
#pragma unroll
    for (int j = 0; j < 4; ++j) o4[j] = (v[j] - mu) * rstd * g4[j] + b4[j];
    *(fx4*)((float*)out + ooff + base + c) = o4;
  } else {
    ushx4 o4;
#pragma unroll
    for (int j = 0; j < 4; ++j) o4[j] = f2b((v[j] - mu) * rstd * g4[j] + b4[j]);
    *(ushx4*)((u16*)out + ooff + base + c) = o4;
  }
}

// ---------------------------------------------------------------------------
extern "C" void kernel_launch(void* const* d_in, const int* in_sizes, int n_in,
                              void* d_out, int out_size, void* d_ws, size_t ws_size,
                              hipStream_t stream) {
  (void)in_sizes; (void)n_in; (void)out_size;
  const void* query = d_in[0];
  const void* keyi  = d_in[1];
  const void* value = d_in[2];
  const int*  mask  = (const int*)d_in[3];
  const void* Wq = d_in[4];
  const void* Wk = d_in[5];
  const void* Wv = d_in[6];
  const void* Wo = d_in[7];
  const void* bo = d_in[8];
  const void* g1 = d_in[9];
  const void* b1 = d_in[10];
  const void* g2 = d_in[11];
  const void* b2 = d_in[12];
  const void* gff = d_in[13];
  const void* bff = d_in[14];
  const void* W1 = d_in[15];
  const void* bf1 = d_in[16];
  const void* W2 = d_in[17];
  const void* bf2 = d_in[18];

  char* p = (char*)d_ws;
  int* flags = (int*)p;
  const int* F = flags;
  const int* Z = flags + 1;
  const int* M = flags + 2;
  dim3 blk(256);

  // footprint(CH) = 4096 + 24MiB (packed weights) + 7*CH*2048 bytes
  const size_t FIXED = 4096 + ((size_t)24 << 20);
  const size_t needC = FIXED + (size_t)8192 * 14336;   // ~142.6 MB
  const size_t needA = FIXED + (size_t)4096 * 14336;   // ~80.0 MB
  const size_t needB = FIXED + (size_t)2048 * 14336;   // ~52.0 MB

  if (ws_size >= needB) {
    // ------------------------- NEW PATH -------------------------
    const int CH = (ws_size >= needC) ? 8192 : (ws_size >= needA) ? 4096 : 2048;
    const int nch = 8192 / CH;

    u16* Wqkv  = (u16*)(p + 4096);                       // [3*1024,1024]
    u16* Wo_bf = Wqkv + (size_t)3 * DM * DM;             // [1024,1024]
    u16* W1T   = Wo_bf + (size_t)DM * DM;                // [4096,1024]
    u16* W2T   = W1T + (size_t)DFF * DM;                 // [1024,4096]
    u16* D0    = W2T + (size_t)DM * DFF;                 // in_bf / h
    u16* D1    = D0 + (size_t)3 * CH * DM;               // qkv / ao,x,xln
    u16* D2    = D1 + (size_t)3 * CH * DM;               // ctx / ff
    u16* qb = D0;
    u16* qkv = D1;
    u16* ao = D1, *x = D1 + (size_t)CH * DM, *xln = D1 + (size_t)2 * CH * DM;
    u16* h = D0;                                         // CH*4096 elems
    u16* ctx = D2, *ff = D2;

    detect_kernel<<<1, 64, 0, stream>>>(query, flags);
    mask_scan<<<dim3(8192), blk, 0, stream>>>(mask, flags);
    pack_w<<<dim3(2048), blk, 0, stream>>>(Wq, Wk, Wv, Wo, Wqkv, Wo_bf, F);
    transpose_any<<<dim3(DFF / 64, DM / 64), blk, 0, stream>>>(W1, W1T, DM, DFF, F);
    transpose_any<<<dim3(DM / 64, DFF / 64), blk, 0, stream>>>(W2, W2T, DFF, DM, F);

    for (int c = 0; c < nch; ++c) {
      const long off = (long)c * CH * DM;
      const long n = (long)CH * DM;
      conv_bf3<<<dim3((int)(n >> 11), 3), blk, 0, stream>>>(query, keyi, value, off, qb, n, F);

      // q/k/v projections co-dispatched: z in {0,1,2}
      gemm_bb<false, false, false><<<dim3((CH / 128) * 8, 3), blk, 0, stream>>>(
          qb, (long)CH * DM, Wqkv, (long)DM * DM, nullptr,
          qkv, 1024L, CH, DM, DM, 3072, Z);

      const int bpc = CH / SEQ, b0 = c * bpc;
      attn_kernel<<<dim3(512, bpc), blk, 0, stream>>>(
          qkv, qkv + 1024, qkv + 2048, 3072,
          mask + (size_t)b0 * SEQ * SEQ, ctx, M);

      gemm_bb<false, true, true><<<dim3((CH / 128) * 8, 1), blk, 0, stream>>>(
          ctx, 0, Wo_bf, 0, bo, ao, 0, CH, DM, DM, DM, F);

      ln_dual<<<dim3(CH), blk, 0, stream>>>(ao, query, off, g1, b1, gff, bff, x, xln, F);

      gemm_bb<true, true, false><<<dim3((CH / 128) * 32, 1), blk, 0, stream>>>(
          xln, 0, W1T, 0, bf1, h, 0, CH, DFF, DM, DFF, F);
      gemm_bb<false, true, true><<<dim3((CH / 128) * 8, 1), blk, 0, stream>>>(
          h, 0, W2T, 0, bf2, ff, 0, CH, DM, DFF, DM, F);

      ln_final<<<dim3(CH), blk, 0, stream>>>(ff, x, g2, b2, d_out, off, F);
    }
  } else {
    // ------------------------- LEGACY PATH (round-3 proven) -------------------------
    const int CH = 2048, FH = 1024;
    const int nch = 8192 / CH;
    const size_t h0 = 4096;
    u16* W1T = (u16*)(p + h0);
    u16* W2T = W1T + (size_t)DFF * DM;
    u16* hb  = (u16*)(p + h0 + ((size_t)16 << 20));
    const size_t HB = (size_t)FH * DFF * 2;
    u16* r0 = (u16*)(p + h0 + ((size_t)16 << 20) + HB);
    const size_t CE = (size_t)CH * DM;
    u16* qp = r0;
    u16* kp = qp + CE;
    u16* vp = kp + CE;
    u16* ctxb = vp + CE;
    u16* x = qp; u16* xln = kp; u16* ao = vp; u16* ff = ctxb;

    detect_kernel<<<1, 64, 0, stream>>>(query, flags);
    mask_scan<<<dim3(8192), blk, 0, stream>>>(mask, flags);
    transpose_any<<<dim3(DFF / 64, DM / 64), blk, 0, stream>>>(W1, W1T, DM, DFF, F);
    transpose_any<<<dim3(DM / 64, DFF / 64), blk, 0, stream>>>(W2, W2T, DFF, DM, F);

    for (int c = 0; c < nch; ++c) {
      const long off = (long)c * CH * DM;
      dim3 gq((CH / 128) * (DM / 128));

      gemm_nt<false, false><<<gq, blk, 0, stream>>>(query, off, Wq, Wq, qp, CH, DM, DM, F, F, Z);
      gemm_nt<false, false><<<gq, blk, 0, stream>>>(keyi,  off, Wk, Wk, kp, CH, DM, DM, F, F, Z);
      gemm_nt<false, false><<<gq, blk, 0, stream>>>(value, off, Wv, Wv, vp, CH, DM, DM, F, F, Z);

      const int bpc = CH / SEQ, b0 = c * bpc;
      for (int bl = 0; bl < bpc; ++bl) {
        const size_t lo = (size_t)bl * SEQ * DM;
        attn_kernel<<<dim3(512, 1), blk, 0, stream>>>(
            qp + lo, kp + lo, vp + lo, 1024,
            mask + (size_t)(b0 + bl) * SEQ * SEQ, ctxb + lo, M);
      }

      gemm_nt<false, true><<<gq, blk, 0, stream>>>(ctxb, 0, Wo, bo, ao, CH, DM, DM, Z, F, F);

      ln_dual<<<dim3(CH), blk, 0, stream>>>(ao, query, off, g1, b1, gff, bff, x, xln, F);

      for (int qs = 0; qs < CH / FH; ++qs) {
        const long so = (long)qs * FH * DM;
        gemm_nt<true, true><<<dim3((FH / 128) * (DFF / 128)), blk, 0, stream>>>(
            xln + so, 0, W1T, bf1, hb, FH, DFF, DM, Z, Z, F);
        gemm_nt<false, true><<<dim3((FH / 128) * (DM / 128)), blk, 0, stream>>>(
            hb, 0, W2T, bf2, ff + so, FH, DM, DFF, Z, Z, F);
      }

      ln_final<<<dim3(CH), blk, 0, stream>>>(ff, x, g2, b2, d_out, off, F);
    }
  }
}